// Round 5
// baseline (431.932 us; speedup 1.0000x reference)
//
#include <hip/hip_runtime.h>
#include <math.h>

#define N_NODES 100000
#define N_EDGES 640000

typedef __bf16 bf16x8 __attribute__((ext_vector_type(8)));
typedef float f32x4 __attribute__((ext_vector_type(4)));

__device__ __forceinline__ unsigned short f2b(float x) {
  unsigned int u = __float_as_uint(x);
  u = (u + 0x7FFFu + ((u >> 16) & 1u)) >> 16;   // RNE
  return (unsigned short)u;
}
__device__ __forceinline__ float blo(unsigned int v) { return __uint_as_float(v << 16); }
__device__ __forceinline__ float bhi(unsigned int v) { return __uint_as_float(v & 0xFFFF0000u); }

// ---------------- edge prep ----------------

__global__ __launch_bounds__(256) void k_init(int* __restrict__ deg, int* __restrict__ counter, int n) {
  int i = blockIdx.x * 256 + threadIdx.x;
  if (i < n) deg[i] = 1;            // self-loop
  if (i == 0) *counter = 0;
}

__global__ __launch_bounds__(256) void k_count(const int* __restrict__ dst, int* __restrict__ deg, int e) {
  int i = blockIdx.x * 256 + threadIdx.x;
  if (i < e) atomicAdd(&deg[dst[i]], 1);
}

__global__ __launch_bounds__(256) void k_alloc(const int* __restrict__ deg, int* __restrict__ row_ptr,
                                               int* __restrict__ fillpos, int* __restrict__ col,
                                               float* __restrict__ dinv, int* __restrict__ counter, int n) {
  __shared__ int sdata[256];
  __shared__ int sbase;
  int tid = threadIdx.x;
  int i = blockIdx.x * 256 + tid;
  int d = (i < n) ? deg[i] : 0;
  sdata[tid] = d;
  __syncthreads();
  for (int off = 1; off < 256; off <<= 1) {
    int v = (tid >= off) ? sdata[tid - off] : 0;
    __syncthreads();
    sdata[tid] += v;
    __syncthreads();
  }
  if (tid == 255) sbase = atomicAdd(counter, sdata[255]);
  __syncthreads();
  int base = sbase;
  if (i < n) {
    int rp = base + sdata[tid] - d;   // exclusive prefix
    row_ptr[i] = rp;
    fillpos[i] = rp + 1;              // slot 0 = self-loop
    col[rp] = i;
    dinv[i] = rsqrtf((float)d);
  }
}

__global__ __launch_bounds__(256) void k_fill(const int* __restrict__ src, const int* __restrict__ dst,
                                              int* __restrict__ fillpos, int* __restrict__ col, int e) {
  int i = blockIdx.x * 256 + threadIdx.x;
  if (i < e) {
    int d = dst[i];
    int p = atomicAdd(&fillpos[d], 1);
    col[p] = src[i];
  }
}

// ---- weight prep: W1/2/3 -> bf16 W^T [128][128]; W4 -> bf16 W^T padded [48][128]; zero rows ----

__global__ __launch_bounds__(256) void k_prepW(const float* __restrict__ W1, const float* __restrict__ W2,
                                               const float* __restrict__ W3, const float* __restrict__ W4,
                                               unsigned short* __restrict__ Wt, unsigned short* __restrict__ Wt4,
                                               unsigned short* __restrict__ Ha, unsigned short* __restrict__ Hc,
                                               unsigned short* __restrict__ H4, int n) {
  int b = blockIdx.x;
  int tid = threadIdx.x;
  if (b < 192) {
    const float* W = (b < 64) ? W1 : (b < 128) ? W2 : W3;
    unsigned short* D = Wt + ((b < 64) ? 0 : (b < 128) ? 16384 : 32768);
    int idx = (b & 63) * 256 + tid;             // [0,16384)
    int k = idx >> 7, nn = idx & 127;
    D[nn * 128 + k] = f2b(W[idx]);
  } else if (b < 216) {
    int idx = (b - 192) * 256 + tid;            // [0,6144)
    int nn = idx >> 7, k = idx & 127;           // nn in [0,48)
    Wt4[nn * 128 + k] = (nn < 40) ? f2b(W4[(size_t)k * 40 + nn]) : (unsigned short)0;
  } else if (b == 216) {
    if (tid < 128) Ha[(size_t)n * 128 + tid] = 0;        // zero row for gathers
    else Hc[(size_t)n * 128 + (tid - 128)] = 0;
  } else {
    if (tid < 48) H4[(size_t)n * 40 + tid] = 0;          // 40 + pad
  }
}

#define SXP 136   // padded LDS stride in bf16 elems (conflict-free per r2/r3 measurements)

// ---------------- layer-1 GEMM: fp32 X read directly, bf16 MFMA, H = dinv*(X W1) ----------------

__global__ __launch_bounds__(256) void k_gemm1(const float* __restrict__ X,
                                               const unsigned short* __restrict__ Wt,
                                               const float* __restrict__ dinv,
                                               unsigned short* __restrict__ H, int n) {
  __shared__ unsigned short sW[128 * SXP];
  int tid = threadIdx.x;
  int row0 = blockIdx.x * 64;
  {
    const uint4* Wt4 = (const uint4*)Wt;
#pragma unroll
    for (int i = 0; i < 8; ++i) {
      int f = tid + i * 256;
      *(uint4*)&sW[(f >> 4) * SXP + (f & 15) * 8] = Wt4[f];
    }
  }
  int wave = tid >> 6, lane = tid & 63;
  int m = lane & 15, q = lane >> 4;
  int grow = row0 + wave * 16 + m;
  if (grow >= n) grow = n - 1;
  const float4* X4 = (const float4*)X;
  uint4 a4[4];
#pragma unroll
  for (int kc = 0; kc < 4; ++kc) {
    float4 f0 = X4[(size_t)grow * 32 + kc * 8 + q * 2];
    float4 f1 = X4[(size_t)grow * 32 + kc * 8 + q * 2 + 1];
    a4[kc].x = (unsigned int)f2b(f0.x) | ((unsigned int)f2b(f0.y) << 16);
    a4[kc].y = (unsigned int)f2b(f0.z) | ((unsigned int)f2b(f0.w) << 16);
    a4[kc].z = (unsigned int)f2b(f1.x) | ((unsigned int)f2b(f1.y) << 16);
    a4[kc].w = (unsigned int)f2b(f1.z) | ((unsigned int)f2b(f1.w) << 16);
  }
  __syncthreads();
  f32x4 acc[8];
#pragma unroll
  for (int ct = 0; ct < 8; ++ct) acc[ct] = (f32x4){0.f, 0.f, 0.f, 0.f};
#pragma unroll
  for (int kc = 0; kc < 4; ++kc) {
    bf16x8 a = *(bf16x8*)&a4[kc];
#pragma unroll
    for (int ct = 0; ct < 8; ++ct) {
      bf16x8 b = *(const bf16x8*)&sW[(ct * 16 + m) * SXP + kc * 32 + q * 8];
      acc[ct] = __builtin_amdgcn_mfma_f32_16x16x32_bf16(a, b, acc[ct], 0, 0, 0);
    }
  }
#pragma unroll
  for (int r = 0; r < 4; ++r) {
    int row = row0 + wave * 16 + q * 4 + r;
    if (row < n) {
      float di = dinv[row];
#pragma unroll
      for (int ct = 0; ct < 8; ++ct)
        H[(size_t)row * 128 + ct * 16 + m] = f2b(acc[ct][r] * di);
    }
  }
}

// ---------------- fused agg(prev layer) + GEMM(next layer) ----------------
// Per wave: aggregate 16 nodes (zero-row trick, 8-deep gather ILP) into LDS A-tile, then MFMA.

__device__ __forceinline__ void agg_tile(const unsigned short* __restrict__ Hprev, const int* __restrict__ col,
                                         const int* __restrict__ row_ptr, const int* __restrict__ deg,
                                         const float* __restrict__ dinv, const float* __restrict__ bias,
                                         unsigned short* __restrict__ sX, int row0, int n, int wave, int lane) {
  const unsigned int* H1 = (const unsigned int*)Hprev;   // 64 uints per row; row n = zeros
  float2 b = ((const float2*)bias)[lane];
  for (int ni = wave * 16; ni < wave * 16 + 16; ++ni) {
    int node = row0 + ni;
    if (node >= n) break;
    int start = row_ptr[node];
    int cnt = deg[node];
    int cnt0 = (cnt < 63) ? cnt : 63;
    int myc = (lane < cnt0) ? col[start + lane] : n;     // invalid lanes -> zero row
    float ax = 0.f, ay = 0.f;
    for (int base = 0; base < cnt0; base += 8) {
#pragma unroll
      for (int jj = 0; jj < 8; ++jj) {
        int idx = base + jj;
        idx = (idx > 63) ? 63 : idx;                     // lane 63 is always zero-row
        int c = __shfl(myc, idx, 64);
        unsigned int v = H1[(size_t)c * 64 + lane];
        ax += blo(v);
        ay += bhi(v);
      }
    }
    for (int j = 63; j < cnt; ++j) {                     // rare deg>=64 tail
      int c = col[start + j];
      unsigned int v = H1[(size_t)c * 64 + lane];
      ax += blo(v);
      ay += bhi(v);
    }
    float di = dinv[node];
    float o0 = fmaf(ax, di, b.x);
    float o1 = fmaf(ay, di, b.y);
    o0 = o0 > 0.f ? o0 : 0.f;
    o1 = o1 > 0.f ? o1 : 0.f;
    *(unsigned int*)&sX[ni * SXP + lane * 2] = (unsigned int)f2b(o0) | ((unsigned int)f2b(o1) << 16);
  }
}

__global__ __launch_bounds__(256) void k_fgemm(const unsigned short* __restrict__ Hprev,
                                               const int* __restrict__ col, const int* __restrict__ row_ptr,
                                               const int* __restrict__ deg, const float* __restrict__ dinv,
                                               const float* __restrict__ bias,
                                               const unsigned short* __restrict__ Wt,
                                               unsigned short* __restrict__ Hnext, int n) {
  __shared__ unsigned short sW[128 * SXP];
  __shared__ unsigned short sX[64 * SXP];
  int tid = threadIdx.x;
  int row0 = blockIdx.x * 64;
  {
    const uint4* Wt4 = (const uint4*)Wt;
#pragma unroll
    for (int i = 0; i < 8; ++i) {
      int f = tid + i * 256;
      *(uint4*)&sW[(f >> 4) * SXP + (f & 15) * 8] = Wt4[f];
    }
  }
  int wave = tid >> 6, lane = tid & 63;
  agg_tile(Hprev, col, row_ptr, deg, dinv, bias, sX, row0, n, wave, lane);
  __syncthreads();
  int m = lane & 15, q = lane >> 4;
  f32x4 acc[8];
#pragma unroll
  for (int ct = 0; ct < 8; ++ct) acc[ct] = (f32x4){0.f, 0.f, 0.f, 0.f};
#pragma unroll
  for (int kc = 0; kc < 4; ++kc) {
    bf16x8 a = *(const bf16x8*)&sX[(wave * 16 + m) * SXP + kc * 32 + q * 8];
#pragma unroll
    for (int ct = 0; ct < 8; ++ct) {
      bf16x8 b = *(const bf16x8*)&sW[(ct * 16 + m) * SXP + kc * 32 + q * 8];
      acc[ct] = __builtin_amdgcn_mfma_f32_16x16x32_bf16(a, b, acc[ct], 0, 0, 0);
    }
  }
#pragma unroll
  for (int r = 0; r < 4; ++r) {
    int row = row0 + wave * 16 + q * 4 + r;
    if (row < n) {
      float di = dinv[row];
#pragma unroll
      for (int ct = 0; ct < 8; ++ct)
        Hnext[(size_t)row * 128 + ct * 16 + m] = f2b(acc[ct][r] * di);
    }
  }
}

// fused agg + layer-4 GEMM (48 padded cols, bf16 out [n+1][40])
__global__ __launch_bounds__(256) void k_fgemm48(const unsigned short* __restrict__ Hprev,
                                                 const int* __restrict__ col, const int* __restrict__ row_ptr,
                                                 const int* __restrict__ deg, const float* __restrict__ dinv,
                                                 const float* __restrict__ bias,
                                                 const unsigned short* __restrict__ Wt4,
                                                 unsigned short* __restrict__ H4, int n) {
  __shared__ unsigned short sW[48 * SXP];
  __shared__ unsigned short sX[64 * SXP];
  int tid = threadIdx.x;
  int row0 = blockIdx.x * 64;
  {
    const uint4* W4 = (const uint4*)Wt4;
#pragma unroll
    for (int i = 0; i < 3; ++i) {
      int f = tid + i * 256;
      *(uint4*)&sW[(f >> 4) * SXP + (f & 15) * 8] = W4[f];
    }
  }
  int wave = tid >> 6, lane = tid & 63;
  agg_tile(Hprev, col, row_ptr, deg, dinv, bias, sX, row0, n, wave, lane);
  __syncthreads();
  int m = lane & 15, q = lane >> 4;
  f32x4 acc[3];
#pragma unroll
  for (int ct = 0; ct < 3; ++ct) acc[ct] = (f32x4){0.f, 0.f, 0.f, 0.f};
#pragma unroll
  for (int kc = 0; kc < 4; ++kc) {
    bf16x8 a = *(const bf16x8*)&sX[(wave * 16 + m) * SXP + kc * 32 + q * 8];
#pragma unroll
    for (int ct = 0; ct < 3; ++ct) {
      bf16x8 b = *(const bf16x8*)&sW[(ct * 16 + m) * SXP + kc * 32 + q * 8];
      acc[ct] = __builtin_amdgcn_mfma_f32_16x16x32_bf16(a, b, acc[ct], 0, 0, 0);
    }
  }
#pragma unroll
  for (int r = 0; r < 4; ++r) {
    int row = row0 + wave * 16 + q * 4 + r;
    if (row < n) {
      float di = dinv[row];
#pragma unroll
      for (int ct = 0; ct < 3; ++ct) {
        int c = ct * 16 + m;
        if (c < 40) H4[(size_t)row * 40 + c] = f2b(acc[ct][r] * di);
      }
    }
  }
}

// ---------------- final aggregation F=40 + bias + log_softmax, 3-neighbor lane slicing ----------------
// Lanes 0..59: slice s = lane/20 gathers neighbor 3j+s; pair p = lane%20 holds classes 2p,2p+1 (uint).

__global__ __launch_bounds__(256) void k_agg40_lsm(const unsigned short* __restrict__ H, const int* __restrict__ col,
                                                   const int* __restrict__ row_ptr, const int* __restrict__ deg,
                                                   const float* __restrict__ dinv, const float* __restrict__ bias,
                                                   float* __restrict__ out, int n) {
  int node = blockIdx.x * 4 + (threadIdx.x >> 6);
  int lane = threadIdx.x & 63;
  if (node >= n) return;
  const unsigned int* H1 = (const unsigned int*)H;   // 20 uints per row; row n = zeros
  int start = row_ptr[node];
  int cnt = deg[node];
  int cnt0 = (cnt < 63) ? cnt : 63;
  int myc = (lane < cnt0) ? col[start + lane] : n;
  int slice = (lane >= 20) + (lane >= 40);
  int pr = lane - slice * 20;
  pr = (pr > 19) ? 19 : pr;                          // lanes 60..63 duplicate slice2/pr19
  int rounds = (cnt0 + 2) / 3;
  float ax = 0.f, ay = 0.f;
  for (int r = 0; r < rounds; ++r) {
    int idx = r * 3 + slice;                         // <= 62, invalid -> zero row
    int c = __shfl(myc, idx, 64);
    unsigned int v = H1[(size_t)c * 20 + pr];
    ax += blo(v);
    ay += bhi(v);
  }
  if (lane < 20) {
    for (int j = 63; j < cnt; ++j) {                 // rare deg>=64 tail
      int c = col[start + j];
      unsigned int v = H1[(size_t)c * 20 + pr];
      ax += blo(v);
      ay += bhi(v);
    }
  }
  // combine the 3 slices into lanes 0..19
  float ax1 = __shfl(ax, lane + 20, 64), ay1 = __shfl(ay, lane + 20, 64);
  float ax2 = __shfl(ax, lane + 40, 64), ay2 = __shfl(ay, lane + 40, 64);
  float di = dinv[node];
  float2 b2 = ((const float2*)bias)[pr];
  float c0 = fmaf(ax + ax1 + ax2, di, b2.x);
  float c1 = fmaf(ay + ay1 + ay2, di, b2.y);
  // log-softmax over 40 classes held as pairs in lanes 0..19
  float v = (lane < 20) ? fmaxf(c0, c1) : -INFINITY;
#pragma unroll
  for (int off = 32; off > 0; off >>= 1) v = fmaxf(v, __shfl_xor(v, off, 64));
  float e = (lane < 20) ? (__expf(c0 - v) + __expf(c1 - v)) : 0.f;
#pragma unroll
  for (int off = 32; off > 0; off >>= 1) e += __shfl_xor(e, off, 64);
  if (lane < 20) {
    float ls = v + __logf(e);
    ((float2*)out)[(size_t)node * 20 + lane] = make_float2(c0 - ls, c1 - ls);
  }
}

// ---------------- launcher ----------------

extern "C" void kernel_launch(void* const* d_in, const int* in_sizes, int n_in,
                              void* d_out, int out_size, void* d_ws, size_t ws_size,
                              hipStream_t stream) {
  const float* x  = (const float*)d_in[0];
  const int* edge = (const int*)d_in[1];
  const float* W1 = (const float*)d_in[2];
  const float* b1 = (const float*)d_in[3];
  const float* W2 = (const float*)d_in[4];
  const float* b2 = (const float*)d_in[5];
  const float* W3 = (const float*)d_in[6];
  const float* b3 = (const float*)d_in[7];
  const float* W4 = (const float*)d_in[8];
  const float* b4 = (const float*)d_in[9];
  float* out = (float*)d_out;

  const int n = N_NODES, E = N_EDGES;
  const int* srcp = edge;        // edge_index[0]
  const int* dstp = edge + E;    // edge_index[1]

  char* ws = (char*)d_ws;
  size_t off = 0;
  auto alloc = [&](size_t bytes) -> void* {
    void* p = ws + off;
    off = (off + bytes + 255) & ~(size_t)255;
    return p;
  };
  int*   deg     = (int*)alloc((size_t)n * 4);
  int*   row_ptr = (int*)alloc((size_t)n * 4);
  int*   fillpos = (int*)alloc((size_t)n * 4);
  float* dinv    = (float*)alloc((size_t)n * 4);
  int*   counter = (int*)alloc(256);
  int*   colx    = (int*)alloc((size_t)(E + n) * 4);
  unsigned short* Ha  = (unsigned short*)alloc((size_t)(n + 1) * 128 * 2);
  unsigned short* Hc  = (unsigned short*)alloc((size_t)(n + 1) * 128 * 2);
  unsigned short* H4  = (unsigned short*)alloc(((size_t)(n + 1) * 40 + 16) * 2);
  unsigned short* Wt  = (unsigned short*)alloc((size_t)3 * 128 * 128 * 2);
  unsigned short* Wt4 = (unsigned short*)alloc((size_t)48 * 128 * 2);
  (void)ws_size; (void)in_sizes; (void)n_in; (void)out_size;

  k_init <<<(n + 255) / 256, 256, 0, stream>>>(deg, counter, n);
  k_count<<<(E + 255) / 256, 256, 0, stream>>>(dstp, deg, E);
  k_alloc<<<(n + 255) / 256, 256, 0, stream>>>(deg, row_ptr, fillpos, colx, dinv, counter, n);
  k_fill <<<(E + 255) / 256, 256, 0, stream>>>(srcp, dstp, fillpos, colx, E);
  k_prepW<<<218, 256, 0, stream>>>(W1, W2, W3, W4, Wt, Wt4, Ha, Hc, H4, n);

  const int gg = (n + 63) / 64, ga = (n + 3) / 4;
  k_gemm1 <<<gg, 256, 0, stream>>>(x, Wt, dinv, Ha, n);                                        // H1
  k_fgemm <<<gg, 256, 0, stream>>>(Ha, colx, row_ptr, deg, dinv, b1, Wt + 16384, Hc, n);       // H2
  k_fgemm <<<gg, 256, 0, stream>>>(Hc, colx, row_ptr, deg, dinv, b2, Wt + 32768, Ha, n);       // H3
  k_fgemm48<<<gg, 256, 0, stream>>>(Ha, colx, row_ptr, deg, dinv, b3, Wt4, H4, n);             // H4
  k_agg40_lsm<<<ga, 256, 0, stream>>>(H4, colx, row_ptr, deg, dinv, b4, out, n);
}

// Round 6
// 363.412 us; speedup vs baseline: 1.1885x; 1.1885x over previous
//
#include <hip/hip_runtime.h>
#include <math.h>

#define N_NODES 100000
#define N_EDGES 640000

typedef __bf16 bf16x8 __attribute__((ext_vector_type(8)));
typedef float f32x4 __attribute__((ext_vector_type(4)));

__device__ __forceinline__ unsigned short f2b(float x) {
  unsigned int u = __float_as_uint(x);
  u = (u + 0x7FFFu + ((u >> 16) & 1u)) >> 16;   // RNE
  return (unsigned short)u;
}
__device__ __forceinline__ float blo(unsigned int v) { return __uint_as_float(v << 16); }
__device__ __forceinline__ float bhi(unsigned int v) { return __uint_as_float(v & 0xFFFF0000u); }

// ---------------- edge prep ----------------

__global__ __launch_bounds__(256) void k_init(int* __restrict__ deg, int* __restrict__ counter, int n) {
  int i = blockIdx.x * 256 + threadIdx.x;
  if (i < n) deg[i] = 1;            // self-loop
  if (i == 0) *counter = 0;
}

__global__ __launch_bounds__(256) void k_count(const int* __restrict__ dst, int* __restrict__ deg, int e) {
  int i = blockIdx.x * 256 + threadIdx.x;
  if (i < e) atomicAdd(&deg[dst[i]], 1);
}

__global__ __launch_bounds__(256) void k_alloc(const int* __restrict__ deg, int* __restrict__ row_ptr,
                                               int* __restrict__ fillpos, int* __restrict__ col,
                                               float* __restrict__ dinv, int* __restrict__ counter, int n) {
  __shared__ int sdata[256];
  __shared__ int sbase;
  int tid = threadIdx.x;
  int i = blockIdx.x * 256 + tid;
  int d = (i < n) ? deg[i] : 0;
  sdata[tid] = d;
  __syncthreads();
  for (int off = 1; off < 256; off <<= 1) {
    int v = (tid >= off) ? sdata[tid - off] : 0;
    __syncthreads();
    sdata[tid] += v;
    __syncthreads();
  }
  if (tid == 255) sbase = atomicAdd(counter, sdata[255]);
  __syncthreads();
  int base = sbase;
  if (i < n) {
    int rp = base + sdata[tid] - d;   // exclusive prefix
    row_ptr[i] = rp;
    fillpos[i] = rp + 1;              // slot 0 = self-loop
    col[rp] = i;
    dinv[i] = rsqrtf((float)d);
  }
}

__global__ __launch_bounds__(256) void k_fill(const int* __restrict__ src, const int* __restrict__ dst,
                                              int* __restrict__ fillpos, int* __restrict__ col, int e) {
  int i = blockIdx.x * 256 + threadIdx.x;
  if (i < e) {
    int d = dst[i];
    int p = atomicAdd(&fillpos[d], 1);
    col[p] = src[i];
  }
}

// ---- weight prep: W1/2/3 -> bf16 W^T [128][128]; W4 -> bf16 W^T padded [48][128]; zero rows ----

__global__ __launch_bounds__(256) void k_prepW(const float* __restrict__ W1, const float* __restrict__ W2,
                                               const float* __restrict__ W3, const float* __restrict__ W4,
                                               unsigned short* __restrict__ Wt, unsigned short* __restrict__ Wt4,
                                               unsigned short* __restrict__ Ha, unsigned short* __restrict__ Hc,
                                               unsigned short* __restrict__ H4, int n) {
  int b = blockIdx.x;
  int tid = threadIdx.x;
  if (b < 192) {
    const float* W = (b < 64) ? W1 : (b < 128) ? W2 : W3;
    unsigned short* D = Wt + ((b < 64) ? 0 : (b < 128) ? 16384 : 32768);
    int idx = (b & 63) * 256 + tid;             // [0,16384)
    int k = idx >> 7, nn = idx & 127;
    D[nn * 128 + k] = f2b(W[idx]);
  } else if (b < 216) {
    int idx = (b - 192) * 256 + tid;            // [0,6144)
    int nn = idx >> 7, k = idx & 127;           // nn in [0,48)
    Wt4[nn * 128 + k] = (nn < 40) ? f2b(W4[(size_t)k * 40 + nn]) : (unsigned short)0;
  } else if (b == 216) {
    if (tid < 128) Ha[(size_t)n * 128 + tid] = 0;        // zero rows for gathers
    else Hc[(size_t)n * 128 + (tid - 128)] = 0;
  } else {
    if (tid < 48) H4[(size_t)n * 40 + tid] = 0;          // 40 + pad
  }
}

#define SXP 136   // padded LDS stride in bf16 elems (conflict-free per r2-r4 measurements)

// ---------------- layer-1 GEMM: fp32 X read directly, bf16 MFMA, H = dinv*(X W1) ----------------

__global__ __launch_bounds__(256) void k_gemm1(const float* __restrict__ X,
                                               const unsigned short* __restrict__ Wt,
                                               const float* __restrict__ dinv,
                                               unsigned short* __restrict__ H, int n) {
  __shared__ unsigned short sW[128 * SXP];
  int tid = threadIdx.x;
  int row0 = blockIdx.x * 64;
  {
    const uint4* Wt4 = (const uint4*)Wt;
#pragma unroll
    for (int i = 0; i < 8; ++i) {
      int f = tid + i * 256;
      *(uint4*)&sW[(f >> 4) * SXP + (f & 15) * 8] = Wt4[f];
    }
  }
  int wave = tid >> 6, lane = tid & 63;
  int m = lane & 15, q = lane >> 4;
  int grow = row0 + wave * 16 + m;
  if (grow >= n) grow = n - 1;
  const float4* X4 = (const float4*)X;
  uint4 a4[4];
#pragma unroll
  for (int kc = 0; kc < 4; ++kc) {
    float4 f0 = X4[(size_t)grow * 32 + kc * 8 + q * 2];
    float4 f1 = X4[(size_t)grow * 32 + kc * 8 + q * 2 + 1];
    a4[kc].x = (unsigned int)f2b(f0.x) | ((unsigned int)f2b(f0.y) << 16);
    a4[kc].y = (unsigned int)f2b(f0.z) | ((unsigned int)f2b(f0.w) << 16);
    a4[kc].z = (unsigned int)f2b(f1.x) | ((unsigned int)f2b(f1.y) << 16);
    a4[kc].w = (unsigned int)f2b(f1.z) | ((unsigned int)f2b(f1.w) << 16);
  }
  __syncthreads();
  f32x4 acc[8];
#pragma unroll
  for (int ct = 0; ct < 8; ++ct) acc[ct] = (f32x4){0.f, 0.f, 0.f, 0.f};
#pragma unroll
  for (int kc = 0; kc < 4; ++kc) {
    bf16x8 a = *(bf16x8*)&a4[kc];
#pragma unroll
    for (int ct = 0; ct < 8; ++ct) {
      bf16x8 b = *(const bf16x8*)&sW[(ct * 16 + m) * SXP + kc * 32 + q * 8];
      acc[ct] = __builtin_amdgcn_mfma_f32_16x16x32_bf16(a, b, acc[ct], 0, 0, 0);
    }
  }
#pragma unroll
  for (int r = 0; r < 4; ++r) {
    int row = row0 + wave * 16 + q * 4 + r;
    if (row < n) {
      float di = dinv[row];
#pragma unroll
      for (int ct = 0; ct < 8; ++ct)
        H[(size_t)row * 128 + ct * 16 + m] = f2b(acc[ct][r] * di);
    }
  }
}

// ---------------- MFMA bf16 GEMM: bf16 X from global, W^T in LDS ----------------

__global__ __launch_bounds__(256) void k_gemmb(const unsigned short* __restrict__ Xb,
                                               const unsigned short* __restrict__ Wt,
                                               const float* __restrict__ dinv,
                                               unsigned short* __restrict__ H, int n) {
  __shared__ unsigned short sW[128 * SXP];
  int tid = threadIdx.x;
  int row0 = blockIdx.x * 64;
  {
    const uint4* Wt4 = (const uint4*)Wt;
#pragma unroll
    for (int i = 0; i < 8; ++i) {
      int f = tid + i * 256;
      *(uint4*)&sW[(f >> 4) * SXP + (f & 15) * 8] = Wt4[f];
    }
  }
  int wave = tid >> 6, lane = tid & 63;
  int m = lane & 15, q = lane >> 4;
  int grow = row0 + wave * 16 + m;
  if (grow >= n) grow = n - 1;
  const uint4* Xb4 = (const uint4*)Xb;
  uint4 a4[4];
#pragma unroll
  for (int kc = 0; kc < 4; ++kc) a4[kc] = Xb4[(size_t)grow * 16 + kc * 4 + q];
  __syncthreads();
  f32x4 acc[8];
#pragma unroll
  for (int ct = 0; ct < 8; ++ct) acc[ct] = (f32x4){0.f, 0.f, 0.f, 0.f};
#pragma unroll
  for (int kc = 0; kc < 4; ++kc) {
    bf16x8 a = *(bf16x8*)&a4[kc];
#pragma unroll
    for (int ct = 0; ct < 8; ++ct) {
      bf16x8 b = *(const bf16x8*)&sW[(ct * 16 + m) * SXP + kc * 32 + q * 8];
      acc[ct] = __builtin_amdgcn_mfma_f32_16x16x32_bf16(a, b, acc[ct], 0, 0, 0);
    }
  }
#pragma unroll
  for (int r = 0; r < 4; ++r) {
    int row = row0 + wave * 16 + q * 4 + r;
    if (row < n) {
      float di = dinv[row];
#pragma unroll
      for (int ct = 0; ct < 8; ++ct)
        H[(size_t)row * 128 + ct * 16 + m] = f2b(acc[ct][r] * di);
    }
  }
}

// ---------------- MFMA bf16 GEMM, 48 padded cols (layer 4), bf16 output [n+1][40] ----------------

__global__ __launch_bounds__(256) void k_gemm48(const unsigned short* __restrict__ Xb,
                                                const unsigned short* __restrict__ Wt4,
                                                const float* __restrict__ dinv,
                                                unsigned short* __restrict__ H, int n) {
  __shared__ unsigned short sW[48 * SXP];
  int tid = threadIdx.x;
  int row0 = blockIdx.x * 64;
  {
    const uint4* W4 = (const uint4*)Wt4;
#pragma unroll
    for (int i = 0; i < 3; ++i) {
      int f = tid + i * 256;                 // [0,768)
      *(uint4*)&sW[(f >> 4) * SXP + (f & 15) * 8] = W4[f];
    }
  }
  int wave = tid >> 6, lane = tid & 63;
  int m = lane & 15, q = lane >> 4;
  int grow = row0 + wave * 16 + m;
  if (grow >= n) grow = n - 1;
  const uint4* Xb4 = (const uint4*)Xb;
  uint4 a4[4];
#pragma unroll
  for (int kc = 0; kc < 4; ++kc) a4[kc] = Xb4[(size_t)grow * 16 + kc * 4 + q];
  __syncthreads();
  f32x4 acc[3];
#pragma unroll
  for (int ct = 0; ct < 3; ++ct) acc[ct] = (f32x4){0.f, 0.f, 0.f, 0.f};
#pragma unroll
  for (int kc = 0; kc < 4; ++kc) {
    bf16x8 a = *(bf16x8*)&a4[kc];
#pragma unroll
    for (int ct = 0; ct < 3; ++ct) {
      bf16x8 b = *(const bf16x8*)&sW[(ct * 16 + m) * SXP + kc * 32 + q * 8];
      acc[ct] = __builtin_amdgcn_mfma_f32_16x16x32_bf16(a, b, acc[ct], 0, 0, 0);
    }
  }
#pragma unroll
  for (int r = 0; r < 4; ++r) {
    int row = row0 + wave * 16 + q * 4 + r;
    if (row < n) {
      float di = dinv[row];
#pragma unroll
      for (int ct = 0; ct < 3; ++ct) {
        int c = ct * 16 + m;
        if (c < 40) H[(size_t)row * 40 + c] = f2b(acc[ct][r] * di);
      }
    }
  }
}

// ---------------- aggregation F=128 bf16: one wave per node, zero-row trick, 8-deep ILP ----------------

__global__ __launch_bounds__(256) void k_aggb(const unsigned short* __restrict__ H, const int* __restrict__ col,
                                              const int* __restrict__ row_ptr, const int* __restrict__ deg,
                                              const float* __restrict__ dinv, const float* __restrict__ bias,
                                              unsigned short* __restrict__ Xout, int n) {
  int node = blockIdx.x * 4 + (threadIdx.x >> 6);
  int lane = threadIdx.x & 63;
  if (node >= n) return;
  const unsigned int* H1 = (const unsigned int*)H;   // 64 uints per row; row n = zeros
  int start = row_ptr[node];
  int cnt = deg[node];
  int cnt0 = (cnt < 63) ? cnt : 63;
  int myc = (lane < cnt0) ? col[start + lane] : n;   // invalid lanes -> zero row
  float ax = 0.f, ay = 0.f;
  for (int base = 0; base < cnt0; base += 8) {
#pragma unroll
    for (int jj = 0; jj < 8; ++jj) {
      int idx = base + jj;
      idx = (idx > 63) ? 63 : idx;                   // lane 63 always holds zero-row index
      int c = __shfl(myc, idx, 64);
      unsigned int v = H1[(size_t)c * 64 + lane];
      ax += blo(v);
      ay += bhi(v);
    }
  }
  for (int j = 63; j < cnt; ++j) {                   // rare deg>=64 tail
    int c = col[start + j];
    unsigned int v = H1[(size_t)c * 64 + lane];
    ax += blo(v);
    ay += bhi(v);
  }
  float di = dinv[node];
  float2 b = ((const float2*)bias)[lane];
  float o0 = fmaf(ax, di, b.x);
  float o1 = fmaf(ay, di, b.y);
  o0 = o0 > 0.f ? o0 : 0.f;
  o1 = o1 > 0.f ? o1 : 0.f;
  ((unsigned int*)Xout)[(size_t)node * 64 + lane] =
      (unsigned int)f2b(o0) | ((unsigned int)f2b(o1) << 16);
}

// ---------------- final aggregation F=40 + bias + log_softmax, 3-neighbor lane slicing ----------------
// Lanes 0..59: slice s = lane/20 gathers neighbor 3j+s; pair p = lane%20 holds classes 2p,2p+1 (uint).

__global__ __launch_bounds__(256) void k_agg40_lsm(const unsigned short* __restrict__ H, const int* __restrict__ col,
                                                   const int* __restrict__ row_ptr, const int* __restrict__ deg,
                                                   const float* __restrict__ dinv, const float* __restrict__ bias,
                                                   float* __restrict__ out, int n) {
  int node = blockIdx.x * 4 + (threadIdx.x >> 6);
  int lane = threadIdx.x & 63;
  if (node >= n) return;
  const unsigned int* H1 = (const unsigned int*)H;   // 20 uints per row; row n = zeros
  int start = row_ptr[node];
  int cnt = deg[node];
  int cnt0 = (cnt < 63) ? cnt : 63;
  int myc = (lane < cnt0) ? col[start + lane] : n;
  int slice = (lane >= 20) + (lane >= 40);
  int pr = lane - slice * 20;
  pr = (pr > 19) ? 19 : pr;                          // lanes 60..63 duplicate slice2/pr19
  int rounds = (cnt0 + 2) / 3;
  float ax = 0.f, ay = 0.f;
  for (int r = 0; r < rounds; ++r) {
    int idx = r * 3 + slice;                         // <= 62, invalid -> zero row
    int c = __shfl(myc, idx, 64);
    unsigned int v = H1[(size_t)c * 20 + pr];
    ax += blo(v);
    ay += bhi(v);
  }
  if (lane < 20) {
    for (int j = 63; j < cnt; ++j) {                 // rare deg>=64 tail
      int c = col[start + j];
      unsigned int v = H1[(size_t)c * 20 + pr];
      ax += blo(v);
      ay += bhi(v);
    }
  }
  // combine the 3 slices into lanes 0..19
  float ax1 = __shfl(ax, lane + 20, 64), ay1 = __shfl(ay, lane + 20, 64);
  float ax2 = __shfl(ax, lane + 40, 64), ay2 = __shfl(ay, lane + 40, 64);
  float di = dinv[node];
  float2 b2 = ((const float2*)bias)[pr];
  float c0 = fmaf(ax + ax1 + ax2, di, b2.x);
  float c1 = fmaf(ay + ay1 + ay2, di, b2.y);
  // log-softmax over 40 classes held as pairs in lanes 0..19
  float v = (lane < 20) ? fmaxf(c0, c1) : -INFINITY;
#pragma unroll
  for (int off = 32; off > 0; off >>= 1) v = fmaxf(v, __shfl_xor(v, off, 64));
  float e = (lane < 20) ? (__expf(c0 - v) + __expf(c1 - v)) : 0.f;
#pragma unroll
  for (int off = 32; off > 0; off >>= 1) e += __shfl_xor(e, off, 64);
  if (lane < 20) {
    float ls = v + __logf(e);
    ((float2*)out)[(size_t)node * 20 + lane] = make_float2(c0 - ls, c1 - ls);
  }
}

// ---------------- launcher ----------------

extern "C" void kernel_launch(void* const* d_in, const int* in_sizes, int n_in,
                              void* d_out, int out_size, void* d_ws, size_t ws_size,
                              hipStream_t stream) {
  const float* x  = (const float*)d_in[0];
  const int* edge = (const int*)d_in[1];
  const float* W1 = (const float*)d_in[2];
  const float* b1 = (const float*)d_in[3];
  const float* W2 = (const float*)d_in[4];
  const float* b2 = (const float*)d_in[5];
  const float* W3 = (const float*)d_in[6];
  const float* b3 = (const float*)d_in[7];
  const float* W4 = (const float*)d_in[8];
  const float* b4 = (const float*)d_in[9];
  float* out = (float*)d_out;

  const int n = N_NODES, E = N_EDGES;
  const int* srcp = edge;        // edge_index[0]
  const int* dstp = edge + E;    // edge_index[1]

  char* ws = (char*)d_ws;
  size_t off = 0;
  auto alloc = [&](size_t bytes) -> void* {
    void* p = ws + off;
    off = (off + bytes + 255) & ~(size_t)255;
    return p;
  };
  int*   deg     = (int*)alloc((size_t)n * 4);
  int*   row_ptr = (int*)alloc((size_t)n * 4);
  int*   fillpos = (int*)alloc((size_t)n * 4);
  float* dinv    = (float*)alloc((size_t)n * 4);
  int*   counter = (int*)alloc(256);
  int*   colx    = (int*)alloc((size_t)(E + n) * 4);
  unsigned short* Ha  = (unsigned short*)alloc((size_t)(n + 1) * 128 * 2);
  unsigned short* Hc  = (unsigned short*)alloc((size_t)(n + 1) * 128 * 2);
  unsigned short* Xc  = (unsigned short*)alloc((size_t)n * 128 * 2);
  unsigned short* H4  = (unsigned short*)alloc(((size_t)(n + 1) * 40 + 16) * 2);
  unsigned short* Wt  = (unsigned short*)alloc((size_t)3 * 128 * 128 * 2);
  unsigned short* Wt4 = (unsigned short*)alloc((size_t)48 * 128 * 2);
  (void)ws_size; (void)in_sizes; (void)n_in; (void)out_size;

  k_init <<<(n + 255) / 256, 256, 0, stream>>>(deg, counter, n);
  k_count<<<(E + 255) / 256, 256, 0, stream>>>(dstp, deg, E);
  k_alloc<<<(n + 255) / 256, 256, 0, stream>>>(deg, row_ptr, fillpos, colx, dinv, counter, n);
  k_fill <<<(E + 255) / 256, 256, 0, stream>>>(srcp, dstp, fillpos, colx, E);
  k_prepW<<<218, 256, 0, stream>>>(W1, W2, W3, W4, Wt, Wt4, Ha, Hc, H4, n);

  const int gg = (n + 63) / 64, ga = (n + 3) / 4;
  // layer 1
  k_gemm1<<<gg, 256, 0, stream>>>(x, Wt, dinv, Ha, n);
  k_aggb <<<ga, 256, 0, stream>>>(Ha, colx, row_ptr, deg, dinv, b1, Xc, n);
  // layer 2
  k_gemmb<<<gg, 256, 0, stream>>>(Xc, Wt + 16384, dinv, Hc, n);
  k_aggb <<<ga, 256, 0, stream>>>(Hc, colx, row_ptr, deg, dinv, b2, Xc, n);
  // layer 3
  k_gemmb<<<gg, 256, 0, stream>>>(Xc, Wt + 32768, dinv, Ha, n);
  k_aggb <<<ga, 256, 0, stream>>>(Ha, colx, row_ptr, deg, dinv, b3, Xc, n);
  // layer 4
  k_gemm48<<<gg, 256, 0, stream>>>(Xc, Wt4, dinv, H4, n);
  k_agg40_lsm<<<ga, 256, 0, stream>>>(H4, colx, row_ptr, deg, dinv, b4, out, n);
}

// Round 7
// 345.062 us; speedup vs baseline: 1.2518x; 1.0532x over previous
//
#include <hip/hip_runtime.h>
#include <math.h>

#define N_NODES 100000
#define N_EDGES 640000

typedef __bf16 bf16x8 __attribute__((ext_vector_type(8)));
typedef float f32x4 __attribute__((ext_vector_type(4)));

__device__ __forceinline__ unsigned short f2b(float x) {
  unsigned int u = __float_as_uint(x);
  u = (u + 0x7FFFu + ((u >> 16) & 1u)) >> 16;   // RNE
  return (unsigned short)u;
}
__device__ __forceinline__ float blo(unsigned int v) { return __uint_as_float(v << 16); }
__device__ __forceinline__ float bhi(unsigned int v) { return __uint_as_float(v & 0xFFFF0000u); }

// ---------------- edge prep ----------------

__global__ __launch_bounds__(256) void k_init(int* __restrict__ deg, int* __restrict__ counter, int n) {
  int i = blockIdx.x * 256 + threadIdx.x;
  if (i < n) deg[i] = 1;            // self-loop
  if (i == 0) *counter = 0;
}

__global__ __launch_bounds__(256) void k_count(const int* __restrict__ dst, int* __restrict__ deg, int e) {
  int i = blockIdx.x * 256 + threadIdx.x;
  if (i < e) atomicAdd(&deg[dst[i]], 1);
}

__global__ __launch_bounds__(256) void k_alloc(const int* __restrict__ deg, int* __restrict__ row_ptr,
                                               int* __restrict__ fillpos, int* __restrict__ col,
                                               float* __restrict__ dinv, int* __restrict__ counter, int n) {
  __shared__ int sdata[256];
  __shared__ int sbase;
  int tid = threadIdx.x;
  int i = blockIdx.x * 256 + tid;
  int d = (i < n) ? deg[i] : 0;
  sdata[tid] = d;
  __syncthreads();
  for (int off = 1; off < 256; off <<= 1) {
    int v = (tid >= off) ? sdata[tid - off] : 0;
    __syncthreads();
    sdata[tid] += v;
    __syncthreads();
  }
  if (tid == 255) sbase = atomicAdd(counter, sdata[255]);
  __syncthreads();
  int base = sbase;
  if (i < n) {
    int rp = base + sdata[tid] - d;   // exclusive prefix
    row_ptr[i] = rp;
    fillpos[i] = rp + 1;              // slot 0 = self-loop
    col[rp] = i;
    dinv[i] = rsqrtf((float)d);
  }
}

__global__ __launch_bounds__(256) void k_fill(const int* __restrict__ src, const int* __restrict__ dst,
                                              int* __restrict__ fillpos, int* __restrict__ col, int e) {
  int i = blockIdx.x * 256 + threadIdx.x;
  if (i < e) {
    int d = dst[i];
    int p = atomicAdd(&fillpos[d], 1);
    col[p] = src[i];
  }
}

// ---- weight prep: W1/2/3 -> bf16 W^T [128][128]; W4 -> bf16 W^T padded [48][128]; zero rows ----

__global__ __launch_bounds__(256) void k_prepW(const float* __restrict__ W1, const float* __restrict__ W2,
                                               const float* __restrict__ W3, const float* __restrict__ W4,
                                               unsigned short* __restrict__ Wt, unsigned short* __restrict__ Wt4,
                                               unsigned short* __restrict__ Ha, unsigned short* __restrict__ Hc,
                                               unsigned short* __restrict__ H4, int n) {
  int b = blockIdx.x;
  int tid = threadIdx.x;
  if (b < 192) {
    const float* W = (b < 64) ? W1 : (b < 128) ? W2 : W3;
    unsigned short* D = Wt + ((b < 64) ? 0 : (b < 128) ? 16384 : 32768);
    int idx = (b & 63) * 256 + tid;             // [0,16384)
    int k = idx >> 7, nn = idx & 127;
    D[nn * 128 + k] = f2b(W[idx]);
  } else if (b < 216) {
    int idx = (b - 192) * 256 + tid;            // [0,6144)
    int nn = idx >> 7, k = idx & 127;           // nn in [0,48)
    Wt4[nn * 128 + k] = (nn < 40) ? f2b(W4[(size_t)k * 40 + nn]) : (unsigned short)0;
  } else if (b == 216) {
    if (tid < 128) Ha[(size_t)n * 128 + tid] = 0;        // zero rows for gathers
    else Hc[(size_t)n * 128 + (tid - 128)] = 0;
  } else {
    if (tid < 48) H4[(size_t)n * 40 + tid] = 0;          // 40 + pad
  }
}

#define SXP 136   // padded LDS stride in bf16 elems (conflict-free per r2-r4 measurements)

// ---------------- layer-1 GEMM: fp32 X read directly, bf16 MFMA, H = dinv*(X W1) ----------------

__global__ __launch_bounds__(256) void k_gemm1(const float* __restrict__ X,
                                               const unsigned short* __restrict__ Wt,
                                               const float* __restrict__ dinv,
                                               unsigned short* __restrict__ H, int n) {
  __shared__ unsigned short sW[128 * SXP];
  int tid = threadIdx.x;
  int row0 = blockIdx.x * 64;
  {
    const uint4* Wt4 = (const uint4*)Wt;
#pragma unroll
    for (int i = 0; i < 8; ++i) {
      int f = tid + i * 256;
      *(uint4*)&sW[(f >> 4) * SXP + (f & 15) * 8] = Wt4[f];
    }
  }
  int wave = tid >> 6, lane = tid & 63;
  int m = lane & 15, q = lane >> 4;
  int grow = row0 + wave * 16 + m;
  if (grow >= n) grow = n - 1;
  const float4* X4 = (const float4*)X;
  uint4 a4[4];
#pragma unroll
  for (int kc = 0; kc < 4; ++kc) {
    float4 f0 = X4[(size_t)grow * 32 + kc * 8 + q * 2];
    float4 f1 = X4[(size_t)grow * 32 + kc * 8 + q * 2 + 1];
    a4[kc].x = (unsigned int)f2b(f0.x) | ((unsigned int)f2b(f0.y) << 16);
    a4[kc].y = (unsigned int)f2b(f0.z) | ((unsigned int)f2b(f0.w) << 16);
    a4[kc].z = (unsigned int)f2b(f1.x) | ((unsigned int)f2b(f1.y) << 16);
    a4[kc].w = (unsigned int)f2b(f1.z) | ((unsigned int)f2b(f1.w) << 16);
  }
  __syncthreads();
  f32x4 acc[8];
#pragma unroll
  for (int ct = 0; ct < 8; ++ct) acc[ct] = (f32x4){0.f, 0.f, 0.f, 0.f};
#pragma unroll
  for (int kc = 0; kc < 4; ++kc) {
    bf16x8 a = *(bf16x8*)&a4[kc];
#pragma unroll
    for (int ct = 0; ct < 8; ++ct) {
      bf16x8 b = *(const bf16x8*)&sW[(ct * 16 + m) * SXP + kc * 32 + q * 8];
      acc[ct] = __builtin_amdgcn_mfma_f32_16x16x32_bf16(a, b, acc[ct], 0, 0, 0);
    }
  }
#pragma unroll
  for (int r = 0; r < 4; ++r) {
    int row = row0 + wave * 16 + q * 4 + r;
    if (row < n) {
      float di = dinv[row];
#pragma unroll
      for (int ct = 0; ct < 8; ++ct)
        H[(size_t)row * 128 + ct * 16 + m] = f2b(acc[ct][r] * di);
    }
  }
}

// ---------------- MFMA bf16 GEMM: bf16 X from global, W^T in LDS ----------------

__global__ __launch_bounds__(256) void k_gemmb(const unsigned short* __restrict__ Xb,
                                               const unsigned short* __restrict__ Wt,
                                               const float* __restrict__ dinv,
                                               unsigned short* __restrict__ H, int n) {
  __shared__ unsigned short sW[128 * SXP];
  int tid = threadIdx.x;
  int row0 = blockIdx.x * 64;
  {
    const uint4* Wt4 = (const uint4*)Wt;
#pragma unroll
    for (int i = 0; i < 8; ++i) {
      int f = tid + i * 256;
      *(uint4*)&sW[(f >> 4) * SXP + (f & 15) * 8] = Wt4[f];
    }
  }
  int wave = tid >> 6, lane = tid & 63;
  int m = lane & 15, q = lane >> 4;
  int grow = row0 + wave * 16 + m;
  if (grow >= n) grow = n - 1;
  const uint4* Xb4 = (const uint4*)Xb;
  uint4 a4[4];
#pragma unroll
  for (int kc = 0; kc < 4; ++kc) a4[kc] = Xb4[(size_t)grow * 16 + kc * 4 + q];
  __syncthreads();
  f32x4 acc[8];
#pragma unroll
  for (int ct = 0; ct < 8; ++ct) acc[ct] = (f32x4){0.f, 0.f, 0.f, 0.f};
#pragma unroll
  for (int kc = 0; kc < 4; ++kc) {
    bf16x8 a = *(bf16x8*)&a4[kc];
#pragma unroll
    for (int ct = 0; ct < 8; ++ct) {
      bf16x8 b = *(const bf16x8*)&sW[(ct * 16 + m) * SXP + kc * 32 + q * 8];
      acc[ct] = __builtin_amdgcn_mfma_f32_16x16x32_bf16(a, b, acc[ct], 0, 0, 0);
    }
  }
#pragma unroll
  for (int r = 0; r < 4; ++r) {
    int row = row0 + wave * 16 + q * 4 + r;
    if (row < n) {
      float di = dinv[row];
#pragma unroll
      for (int ct = 0; ct < 8; ++ct)
        H[(size_t)row * 128 + ct * 16 + m] = f2b(acc[ct][r] * di);
    }
  }
}

// ---------------- MFMA bf16 GEMM, 48 padded cols (layer 4), bf16 output [n+1][40] ----------------

__global__ __launch_bounds__(256) void k_gemm48(const unsigned short* __restrict__ Xb,
                                                const unsigned short* __restrict__ Wt4,
                                                const float* __restrict__ dinv,
                                                unsigned short* __restrict__ H, int n) {
  __shared__ unsigned short sW[48 * SXP];
  int tid = threadIdx.x;
  int row0 = blockIdx.x * 64;
  {
    const uint4* W4 = (const uint4*)Wt4;
#pragma unroll
    for (int i = 0; i < 3; ++i) {
      int f = tid + i * 256;                 // [0,768)
      *(uint4*)&sW[(f >> 4) * SXP + (f & 15) * 8] = W4[f];
    }
  }
  int wave = tid >> 6, lane = tid & 63;
  int m = lane & 15, q = lane >> 4;
  int grow = row0 + wave * 16 + m;
  if (grow >= n) grow = n - 1;
  const uint4* Xb4 = (const uint4*)Xb;
  uint4 a4[4];
#pragma unroll
  for (int kc = 0; kc < 4; ++kc) a4[kc] = Xb4[(size_t)grow * 16 + kc * 4 + q];
  __syncthreads();
  f32x4 acc[3];
#pragma unroll
  for (int ct = 0; ct < 3; ++ct) acc[ct] = (f32x4){0.f, 0.f, 0.f, 0.f};
#pragma unroll
  for (int kc = 0; kc < 4; ++kc) {
    bf16x8 a = *(bf16x8*)&a4[kc];
#pragma unroll
    for (int ct = 0; ct < 3; ++ct) {
      bf16x8 b = *(const bf16x8*)&sW[(ct * 16 + m) * SXP + kc * 32 + q * 8];
      acc[ct] = __builtin_amdgcn_mfma_f32_16x16x32_bf16(a, b, acc[ct], 0, 0, 0);
    }
  }
#pragma unroll
  for (int r = 0; r < 4; ++r) {
    int row = row0 + wave * 16 + q * 4 + r;
    if (row < n) {
      float di = dinv[row];
#pragma unroll
      for (int ct = 0; ct < 3; ++ct) {
        int c = ct * 16 + m;
        if (c < 40) H[(size_t)row * 40 + c] = f2b(acc[ct][r] * di);
      }
    }
  }
}

// ---------------- aggregation F=128 bf16: HALF-wave per node, uint2 gathers, 8-deep ILP ----------------
// 32 lanes x 8 B = one 256 B row per load instruction; 2 nodes per wave -> 4 KB in flight/wave.

__global__ __launch_bounds__(256) void k_aggb(const unsigned short* __restrict__ H, const int* __restrict__ col,
                                              const int* __restrict__ row_ptr, const int* __restrict__ deg,
                                              const float* __restrict__ dinv, const float* __restrict__ bias,
                                              unsigned short* __restrict__ Xout, int n) {
  int node = blockIdx.x * 8 + (threadIdx.x >> 5);
  int hl = threadIdx.x & 31;                         // lane within half-wave
  int halfbase = threadIdx.x & 32;                   // 0 or 32 within the wave
  if (node >= n) return;
  const uint2* H2 = (const uint2*)H;                 // 32 uint2 per row; row n = zeros
  int start = row_ptr[node];
  int cnt = deg[node];
  int cnt0 = (cnt < 31) ? cnt : 31;
  int myc = (hl < cnt0) ? col[start + hl] : n;       // invalid lanes -> zero row
  float a0 = 0.f, a1 = 0.f, a2 = 0.f, a3 = 0.f;
  for (int base = 0; base < cnt0; base += 8) {
    uint2 v[8];
#pragma unroll
    for (int jj = 0; jj < 8; ++jj) {
      int idx = base + jj;                           // <= 31 always
      int c = __shfl(myc, halfbase + idx, 64);
      v[jj] = H2[(size_t)c * 32 + hl];
    }
#pragma unroll
    for (int jj = 0; jj < 8; ++jj) {
      a0 += blo(v[jj].x); a1 += bhi(v[jj].x);
      a2 += blo(v[jj].y); a3 += bhi(v[jj].y);
    }
  }
  for (int j = 31; j < cnt; ++j) {                   // deg>31 tail (rare)
    int c = col[start + j];
    uint2 v = H2[(size_t)c * 32 + hl];
    a0 += blo(v.x); a1 += bhi(v.x);
    a2 += blo(v.y); a3 += bhi(v.y);
  }
  float di = dinv[node];
  float4 b = ((const float4*)bias)[hl];
  float o0 = fmaf(a0, di, b.x);
  float o1 = fmaf(a1, di, b.y);
  float o2 = fmaf(a2, di, b.z);
  float o3 = fmaf(a3, di, b.w);
  o0 = o0 > 0.f ? o0 : 0.f;
  o1 = o1 > 0.f ? o1 : 0.f;
  o2 = o2 > 0.f ? o2 : 0.f;
  o3 = o3 > 0.f ? o3 : 0.f;
  uint2 w;
  w.x = (unsigned int)f2b(o0) | ((unsigned int)f2b(o1) << 16);
  w.y = (unsigned int)f2b(o2) | ((unsigned int)f2b(o3) << 16);
  ((uint2*)Xout)[(size_t)node * 32 + hl] = w;
}

// ---------------- final aggregation F=40 + bias + log_softmax, 3-slice + 4-round prefetch ----------------
// Lanes 0..59: slice s = lane/20 gathers neighbor 3j+s; pair p = lane%20 holds classes 2p,2p+1.

__global__ __launch_bounds__(256) void k_agg40_lsm(const unsigned short* __restrict__ H, const int* __restrict__ col,
                                                   const int* __restrict__ row_ptr, const int* __restrict__ deg,
                                                   const float* __restrict__ dinv, const float* __restrict__ bias,
                                                   float* __restrict__ out, int n) {
  int node = blockIdx.x * 4 + (threadIdx.x >> 6);
  int lane = threadIdx.x & 63;
  if (node >= n) return;
  const unsigned int* H1 = (const unsigned int*)H;   // 20 uints per row; row n = zeros
  int start = row_ptr[node];
  int cnt = deg[node];
  int cnt0 = (cnt < 63) ? cnt : 63;
  int myc = (lane < cnt0) ? col[start + lane] : n;
  int slice = (lane >= 20) + (lane >= 40);
  int pr = lane - slice * 20;
  pr = (pr > 19) ? 19 : pr;                          // lanes 60..63 duplicate slice2/pr19
  int rounds = (cnt0 + 2) / 3;
  float ax = 0.f, ay = 0.f;
  for (int rb = 0; rb < rounds; rb += 4) {           // 4 independent gathers in flight
    unsigned int v[4];
#pragma unroll
    for (int j = 0; j < 4; ++j) {
      int idx = (rb + j) * 3 + slice;
      idx = (idx > 63) ? 63 : idx;                   // lane 63 -> zero row
      int c = __shfl(myc, idx, 64);
      v[j] = H1[(size_t)c * 20 + pr];
    }
#pragma unroll
    for (int j = 0; j < 4; ++j) { ax += blo(v[j]); ay += bhi(v[j]); }
  }
  if (lane < 20) {
    for (int j = 63; j < cnt; ++j) {                 // rare deg>=64 tail
      int c = col[start + j];
      unsigned int v = H1[(size_t)c * 20 + pr];
      ax += blo(v);
      ay += bhi(v);
    }
  }
  // combine the 3 slices into lanes 0..19
  float ax1 = __shfl(ax, lane + 20, 64), ay1 = __shfl(ay, lane + 20, 64);
  float ax2 = __shfl(ax, lane + 40, 64), ay2 = __shfl(ay, lane + 40, 64);
  float di = dinv[node];
  float2 b2 = ((const float2*)bias)[pr];
  float c0 = fmaf(ax + ax1 + ax2, di, b2.x);
  float c1 = fmaf(ay + ay1 + ay2, di, b2.y);
  // log-softmax over 40 classes held as pairs in lanes 0..19
  float v = (lane < 20) ? fmaxf(c0, c1) : -INFINITY;
#pragma unroll
  for (int off = 32; off > 0; off >>= 1) v = fmaxf(v, __shfl_xor(v, off, 64));
  float e = (lane < 20) ? (__expf(c0 - v) + __expf(c1 - v)) : 0.f;
#pragma unroll
  for (int off = 32; off > 0; off >>= 1) e += __shfl_xor(e, off, 64);
  if (lane < 20) {
    float ls = v + __logf(e);
    ((float2*)out)[(size_t)node * 20 + lane] = make_float2(c0 - ls, c1 - ls);
  }
}

// ---------------- launcher ----------------

extern "C" void kernel_launch(void* const* d_in, const int* in_sizes, int n_in,
                              void* d_out, int out_size, void* d_ws, size_t ws_size,
                              hipStream_t stream) {
  const float* x  = (const float*)d_in[0];
  const int* edge = (const int*)d_in[1];
  const float* W1 = (const float*)d_in[2];
  const float* b1 = (const float*)d_in[3];
  const float* W2 = (const float*)d_in[4];
  const float* b2 = (const float*)d_in[5];
  const float* W3 = (const float*)d_in[6];
  const float* b3 = (const float*)d_in[7];
  const float* W4 = (const float*)d_in[8];
  const float* b4 = (const float*)d_in[9];
  float* out = (float*)d_out;

  const int n = N_NODES, E = N_EDGES;
  const int* srcp = edge;        // edge_index[0]
  const int* dstp = edge + E;    // edge_index[1]

  char* ws = (char*)d_ws;
  size_t off = 0;
  auto alloc = [&](size_t bytes) -> void* {
    void* p = ws + off;
    off = (off + bytes + 255) & ~(size_t)255;
    return p;
  };
  int*   deg     = (int*)alloc((size_t)n * 4);
  int*   row_ptr = (int*)alloc((size_t)n * 4);
  int*   fillpos = (int*)alloc((size_t)n * 4);
  float* dinv    = (float*)alloc((size_t)n * 4);
  int*   counter = (int*)alloc(256);
  int*   colx    = (int*)alloc((size_t)(E + n) * 4);
  unsigned short* Ha  = (unsigned short*)alloc((size_t)(n + 1) * 128 * 2);
  unsigned short* Hc  = (unsigned short*)alloc((size_t)(n + 1) * 128 * 2);
  unsigned short* Xc  = (unsigned short*)alloc((size_t)n * 128 * 2);
  unsigned short* H4  = (unsigned short*)alloc(((size_t)(n + 1) * 40 + 16) * 2);
  unsigned short* Wt  = (unsigned short*)alloc((size_t)3 * 128 * 128 * 2);
  unsigned short* Wt4 = (unsigned short*)alloc((size_t)48 * 128 * 2);
  (void)ws_size; (void)in_sizes; (void)n_in; (void)out_size;

  k_init <<<(n + 255) / 256, 256, 0, stream>>>(deg, counter, n);
  k_count<<<(E + 255) / 256, 256, 0, stream>>>(dstp, deg, E);
  k_alloc<<<(n + 255) / 256, 256, 0, stream>>>(deg, row_ptr, fillpos, colx, dinv, counter, n);
  k_fill <<<(E + 255) / 256, 256, 0, stream>>>(srcp, dstp, fillpos, colx, E);
  k_prepW<<<218, 256, 0, stream>>>(W1, W2, W3, W4, Wt, Wt4, Ha, Hc, H4, n);

  const int gg = (n + 63) / 64, ga = (n + 3) / 4, gh = (n + 7) / 8;
  // layer 1
  k_gemm1<<<gg, 256, 0, stream>>>(x, Wt, dinv, Ha, n);
  k_aggb <<<gh, 256, 0, stream>>>(Ha, colx, row_ptr, deg, dinv, b1, Xc, n);
  // layer 2
  k_gemmb<<<gg, 256, 0, stream>>>(Xc, Wt + 16384, dinv, Hc, n);
  k_aggb <<<gh, 256, 0, stream>>>(Hc, colx, row_ptr, deg, dinv, b2, Xc, n);
  // layer 3
  k_gemmb<<<gg, 256, 0, stream>>>(Xc, Wt + 32768, dinv, Ha, n);
  k_aggb <<<gh, 256, 0, stream>>>(Ha, colx, row_ptr, deg, dinv, b3, Xc, n);
  // layer 4
  k_gemm48<<<gg, 256, 0, stream>>>(Xc, Wt4, dinv, H4, n);
  k_agg40_lsm<<<ga, 256, 0, stream>>>(H4, colx, row_ptr, deg, dinv, b4, out, n);
}

// Round 8
// 337.207 us; speedup vs baseline: 1.2809x; 1.0233x over previous
//
#include <hip/hip_runtime.h>
#include <math.h>

#define N_NODES 100000
#define N_EDGES 640000

typedef __bf16 bf16x8 __attribute__((ext_vector_type(8)));
typedef float f32x4 __attribute__((ext_vector_type(4)));

__device__ __forceinline__ unsigned short f2b(float x) {
  unsigned int u = __float_as_uint(x);
  u = (u + 0x7FFFu + ((u >> 16) & 1u)) >> 16;   // RNE
  return (unsigned short)u;
}
__device__ __forceinline__ float blo(unsigned int v) { return __uint_as_float(v << 16); }
__device__ __forceinline__ float bhi(unsigned int v) { return __uint_as_float(v & 0xFFFF0000u); }

// ---------------- edge prep ----------------

__global__ __launch_bounds__(256) void k_count(const int* __restrict__ dst, int* __restrict__ deg, int e) {
  int i = blockIdx.x * 256 + threadIdx.x;
  if (i < e) atomicAdd(&deg[dst[i]], 1);
}

__global__ __launch_bounds__(256) void k_alloc(const int* __restrict__ deg, int* __restrict__ row_ptr,
                                               int* __restrict__ fillpos, int* __restrict__ col,
                                               float* __restrict__ dinv, int* __restrict__ counter, int n) {
  __shared__ int sdata[256];
  __shared__ int sbase;
  int tid = threadIdx.x;
  int i = blockIdx.x * 256 + tid;
  int d = (i < n) ? deg[i] : 0;
  sdata[tid] = d;
  __syncthreads();
  for (int off = 1; off < 256; off <<= 1) {
    int v = (tid >= off) ? sdata[tid - off] : 0;
    __syncthreads();
    sdata[tid] += v;
    __syncthreads();
  }
  if (tid == 255) sbase = atomicAdd(counter, sdata[255]);
  __syncthreads();
  int base = sbase;
  if (i < n) {
    int rp = base + sdata[tid] - d;   // exclusive prefix
    row_ptr[i] = rp;
    fillpos[i] = rp + 1;              // slot 0 = self-loop
    col[rp] = i;
    dinv[i] = rsqrtf((float)d);
  }
}

__global__ __launch_bounds__(256) void k_fill(const int* __restrict__ src, const int* __restrict__ dst,
                                              int* __restrict__ fillpos, int* __restrict__ col, int e) {
  int i = blockIdx.x * 256 + threadIdx.x;
  if (i < e) {
    int d = dst[i];
    int p = atomicAdd(&fillpos[d], 1);
    col[p] = src[i];
  }
}

// ---- merged prep: deg/counter init + W1/2/3 -> bf16 W^T + W4 -> padded W^T + zero rows ----
// blocks 0..390: deg init; 391..582: W123; 583..606: W4; 607: Ha/Hc zero rows; 608: H4 zero row.

__global__ __launch_bounds__(256) void k_prep0(const float* __restrict__ W1, const float* __restrict__ W2,
                                               const float* __restrict__ W3, const float* __restrict__ W4,
                                               unsigned short* __restrict__ Wt, unsigned short* __restrict__ Wt4,
                                               unsigned short* __restrict__ Ha, unsigned short* __restrict__ Hc,
                                               unsigned short* __restrict__ H4,
                                               int* __restrict__ deg, int* __restrict__ counter, int n) {
  int b = blockIdx.x;
  int tid = threadIdx.x;
  if (b < 391) {
    int i = b * 256 + tid;
    if (i < n) deg[i] = 1;            // self-loop
    if (i == 0) *counter = 0;
  } else if (b < 583) {
    int bb = b - 391;
    const float* W = (bb < 64) ? W1 : (bb < 128) ? W2 : W3;
    unsigned short* D = Wt + ((bb < 64) ? 0 : (bb < 128) ? 16384 : 32768);
    int idx = (bb & 63) * 256 + tid;            // [0,16384)
    int k = idx >> 7, nn = idx & 127;
    D[nn * 128 + k] = f2b(W[idx]);
  } else if (b < 607) {
    int idx = (b - 583) * 256 + tid;            // [0,6144)
    int nn = idx >> 7, k = idx & 127;           // nn in [0,48)
    Wt4[nn * 128 + k] = (nn < 40) ? f2b(W4[(size_t)k * 40 + nn]) : (unsigned short)0;
  } else if (b == 607) {
    if (tid < 128) Ha[(size_t)n * 128 + tid] = 0;        // zero rows for gathers
    else Hc[(size_t)n * 128 + (tid - 128)] = 0;
  } else {
    if (tid < 48) H4[(size_t)n * 40 + tid] = 0;          // 40 + pad
  }
}

#define SXP 136   // padded LDS stride in bf16 elems (conflict-free per r2-r4 measurements)

// ---------------- layer-1 GEMM: fp32 X read directly, bf16 MFMA, H = dinv*(X W1) ----------------

__global__ __launch_bounds__(256) void k_gemm1(const float* __restrict__ X,
                                               const unsigned short* __restrict__ Wt,
                                               const float* __restrict__ dinv,
                                               unsigned short* __restrict__ H, int n) {
  __shared__ unsigned short sW[128 * SXP];
  int tid = threadIdx.x;
  int row0 = blockIdx.x * 64;
  {
    const uint4* Wt4 = (const uint4*)Wt;
#pragma unroll
    for (int i = 0; i < 8; ++i) {
      int f = tid + i * 256;
      *(uint4*)&sW[(f >> 4) * SXP + (f & 15) * 8] = Wt4[f];
    }
  }
  int wave = tid >> 6, lane = tid & 63;
  int m = lane & 15, q = lane >> 4;
  int grow = row0 + wave * 16 + m;
  if (grow >= n) grow = n - 1;
  const float4* X4 = (const float4*)X;
  uint4 a4[4];
#pragma unroll
  for (int kc = 0; kc < 4; ++kc) {
    float4 f0 = X4[(size_t)grow * 32 + kc * 8 + q * 2];
    float4 f1 = X4[(size_t)grow * 32 + kc * 8 + q * 2 + 1];
    a4[kc].x = (unsigned int)f2b(f0.x) | ((unsigned int)f2b(f0.y) << 16);
    a4[kc].y = (unsigned int)f2b(f0.z) | ((unsigned int)f2b(f0.w) << 16);
    a4[kc].z = (unsigned int)f2b(f1.x) | ((unsigned int)f2b(f1.y) << 16);
    a4[kc].w = (unsigned int)f2b(f1.z) | ((unsigned int)f2b(f1.w) << 16);
  }
  __syncthreads();
  f32x4 acc[8];
#pragma unroll
  for (int ct = 0; ct < 8; ++ct) acc[ct] = (f32x4){0.f, 0.f, 0.f, 0.f};
#pragma unroll
  for (int kc = 0; kc < 4; ++kc) {
    bf16x8 a = *(bf16x8*)&a4[kc];
#pragma unroll
    for (int ct = 0; ct < 8; ++ct) {
      bf16x8 b = *(const bf16x8*)&sW[(ct * 16 + m) * SXP + kc * 32 + q * 8];
      acc[ct] = __builtin_amdgcn_mfma_f32_16x16x32_bf16(a, b, acc[ct], 0, 0, 0);
    }
  }
#pragma unroll
  for (int r = 0; r < 4; ++r) {
    int row = row0 + wave * 16 + q * 4 + r;
    if (row < n) {
      float di = dinv[row];
#pragma unroll
      for (int ct = 0; ct < 8; ++ct)
        H[(size_t)row * 128 + ct * 16 + m] = f2b(acc[ct][r] * di);
    }
  }
}

// ---------------- MFMA bf16 GEMM: bf16 X from global, W^T in LDS ----------------

__global__ __launch_bounds__(256) void k_gemmb(const unsigned short* __restrict__ Xb,
                                               const unsigned short* __restrict__ Wt,
                                               const float* __restrict__ dinv,
                                               unsigned short* __restrict__ H, int n) {
  __shared__ unsigned short sW[128 * SXP];
  int tid = threadIdx.x;
  int row0 = blockIdx.x * 64;
  {
    const uint4* Wt4 = (const uint4*)Wt;
#pragma unroll
    for (int i = 0; i < 8; ++i) {
      int f = tid + i * 256;
      *(uint4*)&sW[(f >> 4) * SXP + (f & 15) * 8] = Wt4[f];
    }
  }
  int wave = tid >> 6, lane = tid & 63;
  int m = lane & 15, q = lane >> 4;
  int grow = row0 + wave * 16 + m;
  if (grow >= n) grow = n - 1;
  const uint4* Xb4 = (const uint4*)Xb;
  uint4 a4[4];
#pragma unroll
  for (int kc = 0; kc < 4; ++kc) a4[kc] = Xb4[(size_t)grow * 16 + kc * 4 + q];
  __syncthreads();
  f32x4 acc[8];
#pragma unroll
  for (int ct = 0; ct < 8; ++ct) acc[ct] = (f32x4){0.f, 0.f, 0.f, 0.f};
#pragma unroll
  for (int kc = 0; kc < 4; ++kc) {
    bf16x8 a = *(bf16x8*)&a4[kc];
#pragma unroll
    for (int ct = 0; ct < 8; ++ct) {
      bf16x8 b = *(const bf16x8*)&sW[(ct * 16 + m) * SXP + kc * 32 + q * 8];
      acc[ct] = __builtin_amdgcn_mfma_f32_16x16x32_bf16(a, b, acc[ct], 0, 0, 0);
    }
  }
#pragma unroll
  for (int r = 0; r < 4; ++r) {
    int row = row0 + wave * 16 + q * 4 + r;
    if (row < n) {
      float di = dinv[row];
#pragma unroll
      for (int ct = 0; ct < 8; ++ct)
        H[(size_t)row * 128 + ct * 16 + m] = f2b(acc[ct][r] * di);
    }
  }
}

// ---------------- MFMA bf16 GEMM, 48 padded cols (layer 4), bf16 output [n+1][40] ----------------

__global__ __launch_bounds__(256) void k_gemm48(const unsigned short* __restrict__ Xb,
                                                const unsigned short* __restrict__ Wt4,
                                                const float* __restrict__ dinv,
                                                unsigned short* __restrict__ H, int n) {
  __shared__ unsigned short sW[48 * SXP];
  int tid = threadIdx.x;
  int row0 = blockIdx.x * 64;
  {
    const uint4* W4 = (const uint4*)Wt4;
#pragma unroll
    for (int i = 0; i < 3; ++i) {
      int f = tid + i * 256;                 // [0,768)
      *(uint4*)&sW[(f >> 4) * SXP + (f & 15) * 8] = W4[f];
    }
  }
  int wave = tid >> 6, lane = tid & 63;
  int m = lane & 15, q = lane >> 4;
  int grow = row0 + wave * 16 + m;
  if (grow >= n) grow = n - 1;
  const uint4* Xb4 = (const uint4*)Xb;
  uint4 a4[4];
#pragma unroll
  for (int kc = 0; kc < 4; ++kc) a4[kc] = Xb4[(size_t)grow * 16 + kc * 4 + q];
  __syncthreads();
  f32x4 acc[3];
#pragma unroll
  for (int ct = 0; ct < 3; ++ct) acc[ct] = (f32x4){0.f, 0.f, 0.f, 0.f};
#pragma unroll
  for (int kc = 0; kc < 4; ++kc) {
    bf16x8 a = *(bf16x8*)&a4[kc];
#pragma unroll
    for (int ct = 0; ct < 3; ++ct) {
      bf16x8 b = *(const bf16x8*)&sW[(ct * 16 + m) * SXP + kc * 32 + q * 8];
      acc[ct] = __builtin_amdgcn_mfma_f32_16x16x32_bf16(a, b, acc[ct], 0, 0, 0);
    }
  }
#pragma unroll
  for (int r = 0; r < 4; ++r) {
    int row = row0 + wave * 16 + q * 4 + r;
    if (row < n) {
      float di = dinv[row];
#pragma unroll
      for (int ct = 0; ct < 3; ++ct) {
        int c = ct * 16 + m;
        if (c < 40) H[(size_t)row * 40 + c] = f2b(acc[ct][r] * di);
      }
    }
  }
}

// ---------------- aggregation F=128 bf16: QUARTER-wave per node, uint4 gathers, 8-deep ILP ----------------
// 16 lanes x 16 B = one 256 B row; one wave instruction covers 4 distinct rows; 4 nodes/wave.

__global__ __launch_bounds__(256) void k_aggb(const unsigned short* __restrict__ H, const int* __restrict__ col,
                                              const int* __restrict__ row_ptr, const int* __restrict__ deg,
                                              const float* __restrict__ dinv, const float* __restrict__ bias,
                                              unsigned short* __restrict__ Xout, int n) {
  int node = blockIdx.x * 16 + (threadIdx.x >> 4);
  int ql = threadIdx.x & 15;                         // lane within quarter
  int qbase = threadIdx.x & 48;                      // quarter base within wave
  if (node >= n) return;
  const uint4* H4 = (const uint4*)H;                 // 16 uint4 per row; row n = zeros
  int start = row_ptr[node];
  int cnt = deg[node];
  int cnt0 = (cnt < 15) ? cnt : 15;
  int myc = (ql < cnt0) ? col[start + ql] : n;       // invalid lanes -> zero row
  float a0 = 0.f, a1 = 0.f, a2 = 0.f, a3 = 0.f, a4 = 0.f, a5 = 0.f, a6 = 0.f, a7 = 0.f;
  for (int base = 0; base < cnt0; base += 8) {
    uint4 v[8];
#pragma unroll
    for (int jj = 0; jj < 8; ++jj) {
      int idx = base + jj;
      idx = (idx > 15) ? 15 : idx;                   // lane 15 of quarter always zero-row
      int c = __shfl(myc, qbase + idx, 64);
      v[jj] = H4[(size_t)c * 16 + ql];
    }
#pragma unroll
    for (int jj = 0; jj < 8; ++jj) {
      a0 += blo(v[jj].x); a1 += bhi(v[jj].x);
      a2 += blo(v[jj].y); a3 += bhi(v[jj].y);
      a4 += blo(v[jj].z); a5 += bhi(v[jj].z);
      a6 += blo(v[jj].w); a7 += bhi(v[jj].w);
    }
  }
  for (int j = 15; j < cnt; ++j) {                   // deg>15 tail (rare)
    int c = col[start + j];
    uint4 v = H4[(size_t)c * 16 + ql];
    a0 += blo(v.x); a1 += bhi(v.x);
    a2 += blo(v.y); a3 += bhi(v.y);
    a4 += blo(v.z); a5 += bhi(v.z);
    a6 += blo(v.w); a7 += bhi(v.w);
  }
  float di = dinv[node];
  float4 b0 = ((const float4*)bias)[ql * 2];
  float4 b1 = ((const float4*)bias)[ql * 2 + 1];
  float o0 = fmaf(a0, di, b0.x), o1 = fmaf(a1, di, b0.y);
  float o2 = fmaf(a2, di, b0.z), o3 = fmaf(a3, di, b0.w);
  float o4 = fmaf(a4, di, b1.x), o5 = fmaf(a5, di, b1.y);
  float o6 = fmaf(a6, di, b1.z), o7 = fmaf(a7, di, b1.w);
  o0 = o0 > 0.f ? o0 : 0.f; o1 = o1 > 0.f ? o1 : 0.f;
  o2 = o2 > 0.f ? o2 : 0.f; o3 = o3 > 0.f ? o3 : 0.f;
  o4 = o4 > 0.f ? o4 : 0.f; o5 = o5 > 0.f ? o5 : 0.f;
  o6 = o6 > 0.f ? o6 : 0.f; o7 = o7 > 0.f ? o7 : 0.f;
  uint4 w;
  w.x = (unsigned int)f2b(o0) | ((unsigned int)f2b(o1) << 16);
  w.y = (unsigned int)f2b(o2) | ((unsigned int)f2b(o3) << 16);
  w.z = (unsigned int)f2b(o4) | ((unsigned int)f2b(o5) << 16);
  w.w = (unsigned int)f2b(o6) | ((unsigned int)f2b(o7) << 16);
  ((uint4*)Xout)[(size_t)node * 16 + ql] = w;
}

// ---------------- final aggregation F=40 + bias + log_softmax, 3-slice + 4-round prefetch ----------------
// Lanes 0..59: slice s = lane/20 gathers neighbor 3j+s; pair p = lane%20 holds classes 2p,2p+1.

__global__ __launch_bounds__(256) void k_agg40_lsm(const unsigned short* __restrict__ H, const int* __restrict__ col,
                                                   const int* __restrict__ row_ptr, const int* __restrict__ deg,
                                                   const float* __restrict__ dinv, const float* __restrict__ bias,
                                                   float* __restrict__ out, int n) {
  int node = blockIdx.x * 4 + (threadIdx.x >> 6);
  int lane = threadIdx.x & 63;
  if (node >= n) return;
  const unsigned int* H1 = (const unsigned int*)H;   // 20 uints per row; row n = zeros
  int start = row_ptr[node];
  int cnt = deg[node];
  int cnt0 = (cnt < 63) ? cnt : 63;
  int myc = (lane < cnt0) ? col[start + lane] : n;
  int slice = (lane >= 20) + (lane >= 40);
  int pr = lane - slice * 20;
  pr = (pr > 19) ? 19 : pr;                          // lanes 60..63 duplicate slice2/pr19
  int rounds = (cnt0 + 2) / 3;
  float ax = 0.f, ay = 0.f;
  for (int rb = 0; rb < rounds; rb += 4) {           // 4 independent gathers in flight
    unsigned int v[4];
#pragma unroll
    for (int j = 0; j < 4; ++j) {
      int idx = (rb + j) * 3 + slice;
      idx = (idx > 63) ? 63 : idx;                   // lane 63 -> zero row
      int c = __shfl(myc, idx, 64);
      v[j] = H1[(size_t)c * 20 + pr];
    }
#pragma unroll
    for (int j = 0; j < 4; ++j) { ax += blo(v[j]); ay += bhi(v[j]); }
  }
  if (lane < 20) {
    for (int j = 63; j < cnt; ++j) {                 // rare deg>=64 tail
      int c = col[start + j];
      unsigned int v = H1[(size_t)c * 20 + pr];
      ax += blo(v);
      ay += bhi(v);
    }
  }
  // combine the 3 slices into lanes 0..19
  float ax1 = __shfl(ax, lane + 20, 64), ay1 = __shfl(ay, lane + 20, 64);
  float ax2 = __shfl(ax, lane + 40, 64), ay2 = __shfl(ay, lane + 40, 64);
  float di = dinv[node];
  float2 b2 = ((const float2*)bias)[pr];
  float c0 = fmaf(ax + ax1 + ax2, di, b2.x);
  float c1 = fmaf(ay + ay1 + ay2, di, b2.y);
  // log-softmax over 40 classes held as pairs in lanes 0..19
  float v = (lane < 20) ? fmaxf(c0, c1) : -INFINITY;
#pragma unroll
  for (int off = 32; off > 0; off >>= 1) v = fmaxf(v, __shfl_xor(v, off, 64));
  float e = (lane < 20) ? (__expf(c0 - v) + __expf(c1 - v)) : 0.f;
#pragma unroll
  for (int off = 32; off > 0; off >>= 1) e += __shfl_xor(e, off, 64);
  if (lane < 20) {
    float ls = v + __logf(e);
    ((float2*)out)[(size_t)node * 20 + lane] = make_float2(c0 - ls, c1 - ls);
  }
}

// ---------------- launcher ----------------

extern "C" void kernel_launch(void* const* d_in, const int* in_sizes, int n_in,
                              void* d_out, int out_size, void* d_ws, size_t ws_size,
                              hipStream_t stream) {
  const float* x  = (const float*)d_in[0];
  const int* edge = (const int*)d_in[1];
  const float* W1 = (const float*)d_in[2];
  const float* b1 = (const float*)d_in[3];
  const float* W2 = (const float*)d_in[4];
  const float* b2 = (const float*)d_in[5];
  const float* W3 = (const float*)d_in[6];
  const float* b3 = (const float*)d_in[7];
  const float* W4 = (const float*)d_in[8];
  const float* b4 = (const float*)d_in[9];
  float* out = (float*)d_out;

  const int n = N_NODES, E = N_EDGES;
  const int* srcp = edge;        // edge_index[0]
  const int* dstp = edge + E;    // edge_index[1]

  char* ws = (char*)d_ws;
  size_t off = 0;
  auto alloc = [&](size_t bytes) -> void* {
    void* p = ws + off;
    off = (off + bytes + 255) & ~(size_t)255;
    return p;
  };
  int*   deg     = (int*)alloc((size_t)n * 4);
  int*   row_ptr = (int*)alloc((size_t)n * 4);
  int*   fillpos = (int*)alloc((size_t)n * 4);
  float* dinv    = (float*)alloc((size_t)n * 4);
  int*   counter = (int*)alloc(256);
  int*   colx    = (int*)alloc((size_t)(E + n) * 4);
  unsigned short* Ha  = (unsigned short*)alloc((size_t)(n + 1) * 128 * 2);
  unsigned short* Hc  = (unsigned short*)alloc((size_t)(n + 1) * 128 * 2);
  unsigned short* Xc  = (unsigned short*)alloc((size_t)n * 128 * 2);
  unsigned short* H4  = (unsigned short*)alloc(((size_t)(n + 1) * 40 + 16) * 2);
  unsigned short* Wt  = (unsigned short*)alloc((size_t)3 * 128 * 128 * 2);
  unsigned short* Wt4 = (unsigned short*)alloc((size_t)48 * 128 * 2);
  (void)ws_size; (void)in_sizes; (void)n_in; (void)out_size;

  k_prep0<<<609, 256, 0, stream>>>(W1, W2, W3, W4, Wt, Wt4, Ha, Hc, H4, deg, counter, n);
  k_count<<<(E + 255) / 256, 256, 0, stream>>>(dstp, deg, E);
  k_alloc<<<(n + 255) / 256, 256, 0, stream>>>(deg, row_ptr, fillpos, colx, dinv, counter, n);
  k_fill <<<(E + 255) / 256, 256, 0, stream>>>(srcp, dstp, fillpos, colx, E);

  const int gg = (n + 63) / 64, ga = (n + 3) / 4, gq = (n + 15) / 16;
  // layer 1
  k_gemm1<<<gg, 256, 0, stream>>>(x, Wt, dinv, Ha, n);
  k_aggb <<<gq, 256, 0, stream>>>(Ha, colx, row_ptr, deg, dinv, b1, Xc, n);
  // layer 2
  k_gemmb<<<gg, 256, 0, stream>>>(Xc, Wt + 16384, dinv, Hc, n);
  k_aggb <<<gq, 256, 0, stream>>>(Hc, colx, row_ptr, deg, dinv, b2, Xc, n);
  // layer 3
  k_gemmb<<<gg, 256, 0, stream>>>(Xc, Wt + 32768, dinv, Ha, n);
  k_aggb <<<gq, 256, 0, stream>>>(Ha, colx, row_ptr, deg, dinv, b3, Xc, n);
  // layer 4
  k_gemm48<<<gg, 256, 0, stream>>>(Xc, Wt4, dinv, H4, n);
  k_agg40_lsm<<<ga, 256, 0, stream>>>(H4, colx, row_ptr, deg, dinv, b4, out, n);
}